// Round 16
// baseline (136.982 us; speedup 1.0000x reference)
//
#include <hip/hip_runtime.h>
#include <stdint.h>

typedef __attribute__((ext_vector_type(8))) short short8;
typedef __attribute__((ext_vector_type(8))) __bf16 bf16x8;
typedef __attribute__((ext_vector_type(4))) float f32x4;
typedef __attribute__((ext_vector_type(2))) unsigned int u32x2;

#define T_SEQ 2048

// round-to-nearest-even f32 -> bf16
static __device__ __forceinline__ ushort f2bf(float f) {
  uint32_t u = __float_as_uint(f);
  u += 0x7fffu + ((u >> 16) & 1u);
  return (ushort)(u >> 16);
}

// packed f32x2 -> bf16x2 (low = lo, high = hi), HW RNE
static __device__ __forceinline__ uint32_t cvtpk(float lo, float hi) {
  uint32_t r;
  asm("v_cvt_pk_bf16_f32 %0, %1, %2" : "=v"(r) : "v"(lo), "v"(hi));
  return r;
}

static __device__ __forceinline__ f32x4 mfma16(short8 a, short8 b, f32x4 c) {
  return __builtin_amdgcn_mfma_f32_16x16x32_bf16(
      __builtin_bit_cast(bf16x8, a), __builtin_bit_cast(bf16x8, b), c, 0, 0, 0);
}

// async global->LDS, 16B per lane; lds base must be wave-uniform
static __device__ __forceinline__ void gload16(const ushort* g, char* l) {
  __builtin_amdgcn_global_load_lds(
      (const __attribute__((address_space(1))) void*)g,
      (__attribute__((address_space(3))) void*)l, 16, 0, 0);
}

// f32 -> bf16 elementwise; each thread converts 8 elements.
__global__ __launch_bounds__(256) void cvt_bf16_k(const float* __restrict__ in,
                                                  ushort* __restrict__ out) {
  int i = (blockIdx.x * 256 + threadIdx.x) * 8;
  float4 a = *(const float4*)(in + i);
  float4 b = *(const float4*)(in + i + 4);
  short8 o;
  ((ushort*)&o)[0] = f2bf(a.x); ((ushort*)&o)[1] = f2bf(a.y);
  ((ushort*)&o)[2] = f2bf(a.z); ((ushort*)&o)[3] = f2bf(a.w);
  ((ushort*)&o)[4] = f2bf(b.x); ((ushort*)&o)[5] = f2bf(b.y);
  ((ushort*)&o)[6] = f2bf(b.z); ((ushort*)&o)[7] = f2bf(b.w);
  *(short8*)(out + i) = o;
}

// out[n][k] = bf16(in[k][n]) for f32 in[K][N]; grid = (K/64, N/64), 256 threads
__global__ __launch_bounds__(256) void transpose_cvt_k(const float* __restrict__ in,
                                                       ushort* __restrict__ out,
                                                       int K, int N) {
  __shared__ ushort t[64][65];
  const int bk = blockIdx.x * 64, bn = blockIdx.y * 64;
  const int r = threadIdx.x >> 2, c0 = (threadIdx.x & 3) << 4;
  const float* src = in + (size_t)(bk + r) * N + bn + c0;
#pragma unroll
  for (int q = 0; q < 4; ++q) {
    float4 a = *(const float4*)(src + q * 4);
    t[r][c0 + q * 4 + 0] = f2bf(a.x);
    t[r][c0 + q * 4 + 1] = f2bf(a.y);
    t[r][c0 + q * 4 + 2] = f2bf(a.z);
    t[r][c0 + q * 4 + 3] = f2bf(a.w);
  }
  __syncthreads();
  short8 o0, o1;
#pragma unroll
  for (int j = 0; j < 8; ++j) {
    ((ushort*)&o0)[j] = t[c0 + j][r];
    ((ushort*)&o1)[j] = t[c0 + 8 + j][r];
  }
  ushort* dst = out + (size_t)(bn + r) * K + bk + c0;
  *(short8*)(dst) = o0;
  *(short8*)(dst + 8) = o1;
}

// C[M][N] = A[M][K] * Bt[N][K]^T, bf16 in, fp32 accum. (round-10 version)
__global__ __launch_bounds__(256) void gemm_bt(const ushort* __restrict__ A,
                                               const ushort* __restrict__ Bt,
                                               void* __restrict__ Cv,
                                               int Mdim, int Ndim, int Kdim,
                                               int f32out) {
  __shared__ char sA[128 * 128];
  __shared__ char sB[128 * 128];
  const int tid = threadIdx.x;
  const int lane = tid & 63, wid = tid >> 6;
  const int wm = wid >> 1, wn = wid & 1;
  const int lc = lane & 15, lg = lane >> 4;
  const int bm = blockIdx.x * 128, bn = blockIdx.y * 128;
  const int lane16 = lane << 4;

  f32x4 acc[4][4] = {};

  for (int k0 = 0; k0 < Kdim; k0 += 64) {
    __syncthreads();
#pragma unroll
    for (int i = 0; i < 4; ++i) {
      int v = tid + i * 256;
      int row = v >> 3;
      int cbl = (v & 7) << 4;
      int ce = (cbl ^ ((row & 7) << 4)) >> 1;
      char* la = sA + ((v << 4) - lane16);
      char* lb = sB + ((v << 4) - lane16);
      gload16(A + (size_t)(bm + row) * Kdim + k0 + ce, la);
      gload16(Bt + (size_t)(bn + row) * Kdim + k0 + ce, lb);
    }
    __syncthreads();
#pragma unroll
    for (int ks = 0; ks < 2; ++ks) {
      const int kb = ks * 64 + lg * 16;
      short8 af[4], bfr[4];
#pragma unroll
      for (int m = 0; m < 4; ++m) {
        int row = wm * 64 + m * 16 + lc;
        af[m] = *(const short8*)&sA[(row << 7) + (kb ^ ((row & 7) << 4))];
      }
#pragma unroll
      for (int n = 0; n < 4; ++n) {
        int row = wn * 64 + n * 16 + lc;
        bfr[n] = *(const short8*)&sB[(row << 7) + (kb ^ ((row & 7) << 4))];
      }
#pragma unroll
      for (int m = 0; m < 4; ++m)
#pragma unroll
        for (int n = 0; n < 4; ++n)
          acc[m][n] = mfma16(af[m], bfr[n], acc[m][n]);
    }
  }
#pragma unroll
  for (int m = 0; m < 4; ++m) {
    int rowb = bm + wm * 64 + m * 16 + lg * 4;
#pragma unroll
    for (int n = 0; n < 4; ++n) {
      int col = bn + wn * 64 + n * 16 + lc;
      if (f32out) {
        float* C = (float*)Cv;
#pragma unroll
        for (int r = 0; r < 4; ++r)
          C[(size_t)(rowb + r) * Ndim + col] = acc[m][n][r];
      } else {
        ushort* C = (ushort*)Cv;
#pragma unroll
        for (int r = 0; r < 4; ++r)
          C[(size_t)(rowb + r) * Ndim + col] = f2bf(acc[m][n][r]);
      }
    }
  }
}

// Flash attention: one 128-row q-tile per 512-thread block (8 waves x 16 q
// rows), bijective slot map for causal balance + XCD locality (round-15).
// Round-16 change: DOUBLE-BUFFERED K/V LDS, ONE barrier per iteration.
// Iter kb: write staged regs (tile kb+1) -> buf[(kb+1)&1], issue loads for
// tile kb+2, compute from buf[kb&1], barrier. The end-of-iter barrier
// protects buf[(kb+2)&1] (= buf[kb&1]) from next iter's writes.
__global__ __launch_bounds__(512) void attn_k(const ushort* __restrict__ qkv,
                                              ushort* __restrict__ Y) {
  __shared__ char sK[16384];  // 2 x K tile [64 t][64 d], swizzled rows of 128B
  __shared__ char sV[16384];  // 2 x V^T tile [64 d][64 t], swizzled
  __shared__ char sP[16384];  // per-wave P [16 q][64 k] bf16, swizzled
  __shared__ float sL[8][16]; // per-wave reciprocal denominators
  const int tid = threadIdx.x;
  const int lane = tid & 63, wid = tid >> 6;
  const int lc = lane & 15, lg = lane >> 4;
  // slot map: xcd = orig&7 owns bh {4x..4x+3}; slots s and s+32 (same CU
  // under round-robin) get tiles t and 15-t -> 34 k-iters per CU.
  const int orig = blockIdx.x;
  const int xcd = orig & 7, slot = orig >> 3;     // slot 0..63
  int tile, bhl;
  if (slot < 32) { tile = slot >> 2;              bhl = slot & 3; }
  else           { tile = 15 - ((slot - 32) >> 2); bhl = (slot - 32) & 3; }
  const int bh = xcd * 4 + bhl;
  const int b = bh >> 4, h = bh & 15;
  char* sPw = sP + (wid << 11);

  const ushort* base = qkv + (size_t)b * T_SEQ * 3072 + h * 64;
  const int q0 = tile * 128 + wid * 16;           // 16 q-rows per wave

  const int kt = tid >> 3, kce = (tid & 7) << 3, kcb = kce << 1;
  const int ksw = (kt & 7) << 4;
  const int vt = tid & 63, vd0 = (tid >> 6) << 3;
  const ushort* kbase = base + 1024;
  const ushort* vbase = base + 2048;

  short8 qf[2];
#pragma unroll
  for (int ks = 0; ks < 2; ++ks)
    qf[ks] = *(const short8*)(base + (size_t)(q0 + lc) * 3072 + ks * 32 + lg * 8);

  f32x4 o[4] = {};
  float lsum = 0.f;

  const float cexp = 0.125f * 1.4426950408889634f;  // scale * log2(e)
  const int nkb = 2 * (tile + 1);
  const int qmaxw = q0 + 15;

  // prologue: stage tile 0 into buf0; issue tile-1 loads
  short8 kr = *(const short8*)(kbase + (size_t)kt * 3072 + kce);
  short8 vr = *(const short8*)(vbase + (size_t)vt * 3072 + vd0);
  *(short8*)&sK[(kt << 7) + (kcb ^ ksw)] = kr;
#pragma unroll
  for (int j = 0; j < 8; ++j) {
    int d = vd0 + j;
    *(ushort*)&sV[(d << 7) + ((2 * vt) ^ ((d & 7) << 4))] = ((const ushort*)&vr)[j];
  }
  if (nkb > 1) {
    kr = *(const short8*)(kbase + (size_t)(64 + kt) * 3072 + kce);
    vr = *(const short8*)(vbase + (size_t)(64 + vt) * 3072 + vd0);
  }
  __syncthreads();

  for (int kb = 0; kb < nkb; ++kb) {
    const int cur = (kb & 1) << 13, nxt = (~kb & 1) << 13;
    // write tile kb+1 into the other buffer (its last readers were iter
    // kb-1, protected by the end-of-iter barrier)
    if (kb + 1 < nkb) {
      *(short8*)&sK[nxt + (kt << 7) + (kcb ^ ksw)] = kr;
#pragma unroll
      for (int j = 0; j < 8; ++j) {
        int d = vd0 + j;
        *(ushort*)&sV[nxt + (d << 7) + ((2 * vt) ^ ((d & 7) << 4))] =
            ((const ushort*)&vr)[j];
      }
    }
    // issue tile kb+2 loads; ~full iteration of latency cover
    if (kb + 2 < nkb) {
      kr = *(const short8*)(kbase + (size_t)((kb + 2) * 64 + kt) * 3072 + kce);
      vr = *(const short8*)(vbase + (size_t)((kb + 2) * 64 + vt) * 3072 + vd0);
    }
    if (kb * 64 <= qmaxw) {
      const char* sKj = sK + cur;
      const char* sVj = sV + cur;
      // S^T = K Q^T: lane holds S^T[k = n*16 + lg*4 + r][q = lc]
      f32x4 S[4] = {};
      __builtin_amdgcn_s_setprio(1);
#pragma unroll
      for (int ks = 0; ks < 2; ++ks) {
        int kbyt = ks * 64 + lg * 16;
        short8 kf[4];
#pragma unroll
        for (int n = 0; n < 4; ++n) {
          int row = n * 16 + lc;
          kf[n] = *(const short8*)&sKj[(row << 7) + (kbyt ^ ((row & 7) << 4))];
        }
#pragma unroll
        for (int n = 0; n < 4; ++n)
          S[n] = mfma16(kf[n], qf[ks], S[n]);
      }
      __builtin_amdgcn_s_setprio(0);

      const bool diag = (kb * 64 + 63 > q0);
      {
        int q = q0 + lc;
        float lacc = 0.f;
#pragma unroll
        for (int n = 0; n < 4; ++n) {
          int kg = kb * 64 + n * 16 + lg * 4;
          f32x4 pe;
#pragma unroll
          for (int r = 0; r < 4; ++r) {
            pe[r] = exp2f(S[n][r] * cexp);
            if (diag && (kg + r > q)) pe[r] = 0.f;   // causal
          }
          lacc += (pe[0] + pe[1]) + (pe[2] + pe[3]);
          u32x2 w;
          w[0] = cvtpk(pe[0], pe[1]);
          w[1] = cvtpk(pe[2], pe[3]);
          int colb = n * 32 + lg * 8;        // P byte col = k*2
          *(u32x2*)&sPw[(lc << 7) + (colb ^ ((lc & 7) << 4))] = w;
        }
        lsum += lacc;
      }
      // fence: b64 P-writes above, b128 pf-reads below (same-wave LDS dep)
      asm volatile("" ::: "memory");
      // O += P V
      __builtin_amdgcn_s_setprio(1);
#pragma unroll
      for (int ks = 0; ks < 2; ++ks) {
        int kbyt = ks * 64 + lg * 16;
        short8 pf = *(const short8*)&sPw[(lc << 7) + (kbyt ^ ((lc & 7) << 4))];
        short8 vf[4];
#pragma unroll
        for (int dn = 0; dn < 4; ++dn) {
          int row = dn * 16 + lc;
          vf[dn] = *(const short8*)&sVj[(row << 7) + (kbyt ^ ((row & 7) << 4))];
        }
#pragma unroll
        for (int dn = 0; dn < 4; ++dn)
          o[dn] = mfma16(pf, vf[dn], o[dn]);
      }
      __builtin_amdgcn_s_setprio(0);
    }
    __syncthreads();   // single barrier per iteration
  }
  // epilogue: reduce l across lane-groups, redistribute via sL, store
  {
    float v = lsum;
    v += __shfl_xor(v, 16);
    v += __shfl_xor(v, 32);
    sL[wid][lc] = 1.0f / v;
  }
  asm volatile("" ::: "memory");
  {
    float lr[4];
#pragma unroll
    for (int r = 0; r < 4; ++r) lr[r] = sL[wid][lg * 4 + r];
#pragma unroll
    for (int dn = 0; dn < 4; ++dn) {
#pragma unroll
      for (int r = 0; r < 4; ++r) {
        int t = q0 + lg * 4 + r;
        Y[(size_t)(b * T_SEQ + t) * 1024 + h * 64 + dn * 16 + lc] =
            f2bf(o[dn][r] * lr[r]);
      }
    }
  }
}

extern "C" void kernel_launch(void* const* d_in, const int* in_sizes, int n_in,
                              void* d_out, int out_size, void* d_ws, size_t ws_size,
                              hipStream_t stream) {
  const float* x    = (const float*)d_in[0];  // [4096][1024] f32
  const float* Wqkv = (const float*)d_in[1];  // [1024][3072] f32
  const float* Wo   = (const float*)d_in[2];  // [1024][1024] f32
  for (int i = 0; i < n_in; ++i) {
    if (in_sizes[i] == 4194304) x = (const float*)d_in[i];
    else if (in_sizes[i] == 3145728) Wqkv = (const float*)d_in[i];
    else if (in_sizes[i] == 1048576) Wo = (const float*)d_in[i];
  }
  float* out = (float*)d_out;  // [4096][1024] f32

  ushort* xb    = (ushort*)d_ws;                       // [4096][1024] bf16
  ushort* WqkvT = xb + (size_t)4096 * 1024;            // [3072][1024]
  ushort* WoT   = WqkvT + (size_t)3072 * 1024;         // [1024][1024]
  ushort* QKV   = WoT + (size_t)1024 * 1024;           // [4096][3072]
  ushort* Yb    = QKV + (size_t)4096 * 3072;           // [4096][1024]

  cvt_bf16_k<<<2048, 256, 0, stream>>>(x, xb);
  transpose_cvt_k<<<dim3(16, 48), 256, 0, stream>>>(Wqkv, WqkvT, 1024, 3072);
  transpose_cvt_k<<<dim3(16, 16), 256, 0, stream>>>(Wo, WoT, 1024, 1024);
  gemm_bt<<<dim3(32, 24), 256, 0, stream>>>(xb, WqkvT, QKV, 4096, 3072, 1024, 0);
  attn_k<<<512, 512, 0, stream>>>(QKV, Yb);
  gemm_bt<<<dim3(32, 8), 256, 0, stream>>>(Yb, WoT, out, 4096, 1024, 1024, 1);
}

// Round 17
// 125.700 us; speedup vs baseline: 1.0898x; 1.0898x over previous
//
#include <hip/hip_runtime.h>
#include <stdint.h>

typedef __attribute__((ext_vector_type(8))) short short8;
typedef __attribute__((ext_vector_type(8))) __bf16 bf16x8;
typedef __attribute__((ext_vector_type(4))) float f32x4;
typedef __attribute__((ext_vector_type(2))) unsigned int u32x2;

#define T_SEQ 2048

// round-to-nearest-even f32 -> bf16
static __device__ __forceinline__ ushort f2bf(float f) {
  uint32_t u = __float_as_uint(f);
  u += 0x7fffu + ((u >> 16) & 1u);
  return (ushort)(u >> 16);
}

// packed f32x2 -> bf16x2 (low = lo, high = hi), HW RNE
static __device__ __forceinline__ uint32_t cvtpk(float lo, float hi) {
  uint32_t r;
  asm("v_cvt_pk_bf16_f32 %0, %1, %2" : "=v"(r) : "v"(lo), "v"(hi));
  return r;
}

static __device__ __forceinline__ f32x4 mfma16(short8 a, short8 b, f32x4 c) {
  return __builtin_amdgcn_mfma_f32_16x16x32_bf16(
      __builtin_bit_cast(bf16x8, a), __builtin_bit_cast(bf16x8, b), c, 0, 0, 0);
}

// async global->LDS, 16B per lane; lds base must be wave-uniform
static __device__ __forceinline__ void gload16(const ushort* g, char* l) {
  __builtin_amdgcn_global_load_lds(
      (const __attribute__((address_space(1))) void*)g,
      (__attribute__((address_space(3))) void*)l, 16, 0, 0);
}

// f32 -> bf16 elementwise; each thread converts 8 elements.
__global__ __launch_bounds__(256) void cvt_bf16_k(const float* __restrict__ in,
                                                  ushort* __restrict__ out) {
  int i = (blockIdx.x * 256 + threadIdx.x) * 8;
  float4 a = *(const float4*)(in + i);
  float4 b = *(const float4*)(in + i + 4);
  short8 o;
  ((ushort*)&o)[0] = f2bf(a.x); ((ushort*)&o)[1] = f2bf(a.y);
  ((ushort*)&o)[2] = f2bf(a.z); ((ushort*)&o)[3] = f2bf(a.w);
  ((ushort*)&o)[4] = f2bf(b.x); ((ushort*)&o)[5] = f2bf(b.y);
  ((ushort*)&o)[6] = f2bf(b.z); ((ushort*)&o)[7] = f2bf(b.w);
  *(short8*)(out + i) = o;
}

// Fused weight transpose+cvt: one launch handles Wqkv (by<48) and Wo.
// out[n][k] = bf16(in[k][n]); K=1024 for both. grid (16, 64), 256 threads.
__global__ __launch_bounds__(256) void transpose_cvt2_k(
    const float* __restrict__ Wqkv, const float* __restrict__ Wo,
    ushort* __restrict__ WqkvT, ushort* __restrict__ WoT) {
  __shared__ ushort t[64][65];
  const int K = 1024;
  const float* in;
  ushort* out;
  int N, byl;
  if (blockIdx.y < 48) { in = Wqkv; out = WqkvT; N = 3072; byl = blockIdx.y; }
  else                 { in = Wo;   out = WoT;   N = 1024; byl = blockIdx.y - 48; }
  const int bk = blockIdx.x * 64, bn = byl * 64;
  const int r = threadIdx.x >> 2, c0 = (threadIdx.x & 3) << 4;
  const float* src = in + (size_t)(bk + r) * N + bn + c0;
#pragma unroll
  for (int q = 0; q < 4; ++q) {
    float4 a = *(const float4*)(src + q * 4);
    t[r][c0 + q * 4 + 0] = f2bf(a.x);
    t[r][c0 + q * 4 + 1] = f2bf(a.y);
    t[r][c0 + q * 4 + 2] = f2bf(a.z);
    t[r][c0 + q * 4 + 3] = f2bf(a.w);
  }
  __syncthreads();
  short8 o0, o1;
#pragma unroll
  for (int j = 0; j < 8; ++j) {
    ((ushort*)&o0)[j] = t[c0 + j][r];
    ((ushort*)&o1)[j] = t[c0 + 8 + j][r];
  }
  ushort* dst = out + (size_t)(bn + r) * K + bk + c0;
  *(short8*)(dst) = o0;
  *(short8*)(dst + 8) = o1;
}

// C[M][N] = A[M][K] * Bt[N][K]^T, bf16 in, fp32 accum. (round-10 version)
__global__ __launch_bounds__(256) void gemm_bt(const ushort* __restrict__ A,
                                               const ushort* __restrict__ Bt,
                                               void* __restrict__ Cv,
                                               int Mdim, int Ndim, int Kdim,
                                               int f32out) {
  __shared__ char sA[128 * 128];
  __shared__ char sB[128 * 128];
  const int tid = threadIdx.x;
  const int lane = tid & 63, wid = tid >> 6;
  const int wm = wid >> 1, wn = wid & 1;
  const int lc = lane & 15, lg = lane >> 4;
  const int bm = blockIdx.x * 128, bn = blockIdx.y * 128;
  const int lane16 = lane << 4;

  f32x4 acc[4][4] = {};

  for (int k0 = 0; k0 < Kdim; k0 += 64) {
    __syncthreads();
#pragma unroll
    for (int i = 0; i < 4; ++i) {
      int v = tid + i * 256;
      int row = v >> 3;
      int cbl = (v & 7) << 4;
      int ce = (cbl ^ ((row & 7) << 4)) >> 1;
      char* la = sA + ((v << 4) - lane16);
      char* lb = sB + ((v << 4) - lane16);
      gload16(A + (size_t)(bm + row) * Kdim + k0 + ce, la);
      gload16(Bt + (size_t)(bn + row) * Kdim + k0 + ce, lb);
    }
    __syncthreads();
#pragma unroll
    for (int ks = 0; ks < 2; ++ks) {
      const int kb = ks * 64 + lg * 16;
      short8 af[4], bfr[4];
#pragma unroll
      for (int m = 0; m < 4; ++m) {
        int row = wm * 64 + m * 16 + lc;
        af[m] = *(const short8*)&sA[(row << 7) + (kb ^ ((row & 7) << 4))];
      }
#pragma unroll
      for (int n = 0; n < 4; ++n) {
        int row = wn * 64 + n * 16 + lc;
        bfr[n] = *(const short8*)&sB[(row << 7) + (kb ^ ((row & 7) << 4))];
      }
#pragma unroll
      for (int m = 0; m < 4; ++m)
#pragma unroll
        for (int n = 0; n < 4; ++n)
          acc[m][n] = mfma16(af[m], bfr[n], acc[m][n]);
    }
  }
#pragma unroll
  for (int m = 0; m < 4; ++m) {
    int rowb = bm + wm * 64 + m * 16 + lg * 4;
#pragma unroll
    for (int n = 0; n < 4; ++n) {
      int col = bn + wn * 64 + n * 16 + lc;
      if (f32out) {
        float* C = (float*)Cv;
#pragma unroll
        for (int r = 0; r < 4; ++r)
          C[(size_t)(rowb + r) * Ndim + col] = acc[m][n][r];
      } else {
        ushort* C = (ushort*)Cv;
#pragma unroll
        for (int r = 0; r < 4; ++r)
          C[(size_t)(rowb + r) * Ndim + col] = f2bf(acc[m][n][r]);
      }
    }
  }
}

// Flash attention (round-15 version, best measured: 52.8 us): one 128-row
// q-tile per 512-thread block (8 waves x 16 q rows) -> 2 blocks/CU = 16
// waves/CU. Bijective slot map: causal balance (CU gets tiles t and 15-t)
// + XCD locality (bh fixed per XCD). Single-tile staging, 2 barriers/iter,
// reg-prefetched K/V, swapped QK^T, fixed-max softmax, deferred denominator.
__global__ __launch_bounds__(512) void attn_k(const ushort* __restrict__ qkv,
                                              ushort* __restrict__ Y) {
  __shared__ char sK[8192];   // K tile [64 t][64 d], swizzled rows of 128B
  __shared__ char sV[8192];   // V^T tile [64 d][64 t], swizzled
  __shared__ char sP[16384];  // per-wave P [16 q][64 k] bf16, swizzled
  __shared__ float sL[8][16]; // per-wave reciprocal denominators
  const int tid = threadIdx.x;
  const int lane = tid & 63, wid = tid >> 6;
  const int lc = lane & 15, lg = lane >> 4;
  const int orig = blockIdx.x;
  const int xcd = orig & 7, slot = orig >> 3;     // slot 0..63
  int tile, bhl;
  if (slot < 32) { tile = slot >> 2;              bhl = slot & 3; }
  else           { tile = 15 - ((slot - 32) >> 2); bhl = (slot - 32) & 3; }
  const int bh = xcd * 4 + bhl;
  const int b = bh >> 4, h = bh & 15;
  char* sPw = sP + (wid << 11);

  const ushort* base = qkv + (size_t)b * T_SEQ * 3072 + h * 64;
  const int q0 = tile * 128 + wid * 16;           // 16 q-rows per wave

  const int kt = tid >> 3, kce = (tid & 7) << 3, kcb = kce << 1;
  const int ksw = (kt & 7) << 4;
  const int vt = tid & 63, vd0 = (tid >> 6) << 3;
  const ushort* kbase = base + 1024;
  const ushort* vbase = base + 2048;

  short8 qf[2];
#pragma unroll
  for (int ks = 0; ks < 2; ++ks)
    qf[ks] = *(const short8*)(base + (size_t)(q0 + lc) * 3072 + ks * 32 + lg * 8);

  f32x4 o[4] = {};
  float lsum = 0.f;

  const float cexp = 0.125f * 1.4426950408889634f;  // scale * log2(e)
  const int nkb = 2 * (tile + 1);
  const int qmaxw = q0 + 15;

  short8 kr = *(const short8*)(kbase + (size_t)kt * 3072 + kce);
  short8 vr = *(const short8*)(vbase + (size_t)vt * 3072 + vd0);

  for (int kb = 0; kb < nkb; ++kb) {
    __syncthreads();   // LDS free
    *(short8*)&sK[(kt << 7) + (kcb ^ ksw)] = kr;
#pragma unroll
    for (int j = 0; j < 8; ++j) {
      int d = vd0 + j;
      *(ushort*)&sV[(d << 7) + ((2 * vt) ^ ((d & 7) << 4))] = ((const ushort*)&vr)[j];
    }
    __syncthreads();   // LDS ready
    if (kb + 1 < nkb) {  // prefetch next tile; latency hides under compute
      kr = *(const short8*)(kbase + (size_t)((kb + 1) * 64 + kt) * 3072 + kce);
      vr = *(const short8*)(vbase + (size_t)((kb + 1) * 64 + vt) * 3072 + vd0);
    }
    if (kb * 64 > qmaxw) continue;  // wave done; staging stays uniform

    // S^T = K Q^T: lane holds S^T[k = n*16 + lg*4 + r][q = lc]
    f32x4 S[4] = {};
    __builtin_amdgcn_s_setprio(1);
#pragma unroll
    for (int ks = 0; ks < 2; ++ks) {
      int kbyt = ks * 64 + lg * 16;
      short8 kf[4];
#pragma unroll
      for (int n = 0; n < 4; ++n) {
        int row = n * 16 + lc;
        kf[n] = *(const short8*)&sK[(row << 7) + (kbyt ^ ((row & 7) << 4))];
      }
#pragma unroll
      for (int n = 0; n < 4; ++n)
        S[n] = mfma16(kf[n], qf[ks], S[n]);
    }
    __builtin_amdgcn_s_setprio(0);

    const bool diag = (kb * 64 + 63 > q0);
    {
      int q = q0 + lc;
      float lacc = 0.f;
#pragma unroll
      for (int n = 0; n < 4; ++n) {
        int kg = kb * 64 + n * 16 + lg * 4;
        f32x4 pe;
#pragma unroll
        for (int r = 0; r < 4; ++r) {
          pe[r] = exp2f(S[n][r] * cexp);
          if (diag && (kg + r > q)) pe[r] = 0.f;   // causal
        }
        lacc += (pe[0] + pe[1]) + (pe[2] + pe[3]);
        u32x2 w;
        w[0] = cvtpk(pe[0], pe[1]);
        w[1] = cvtpk(pe[2], pe[3]);
        int colb = n * 32 + lg * 8;        // P byte col = k*2
        *(u32x2*)&sPw[(lc << 7) + (colb ^ ((lc & 7) << 4))] = w;
      }
      lsum += lacc;
    }
    // fence: b64 P-writes above, b128 pf-reads below (same-wave LDS dep)
    asm volatile("" ::: "memory");
    // O += P V
    __builtin_amdgcn_s_setprio(1);
#pragma unroll
    for (int ks = 0; ks < 2; ++ks) {
      int kbyt = ks * 64 + lg * 16;
      short8 pf = *(const short8*)&sPw[(lc << 7) + (kbyt ^ ((lc & 7) << 4))];
      short8 vf[4];
#pragma unroll
      for (int dn = 0; dn < 4; ++dn) {
        int row = dn * 16 + lc;
        vf[dn] = *(const short8*)&sV[(row << 7) + (kbyt ^ ((row & 7) << 4))];
      }
#pragma unroll
      for (int dn = 0; dn < 4; ++dn)
        o[dn] = mfma16(pf, vf[dn], o[dn]);
    }
    __builtin_amdgcn_s_setprio(0);
  }
  // epilogue: reduce l across lane-groups, redistribute via sL, store
  {
    float v = lsum;
    v += __shfl_xor(v, 16);
    v += __shfl_xor(v, 32);
    sL[wid][lc] = 1.0f / v;
  }
  asm volatile("" ::: "memory");
  {
    float lr[4];
#pragma unroll
    for (int r = 0; r < 4; ++r) lr[r] = sL[wid][lg * 4 + r];
#pragma unroll
    for (int dn = 0; dn < 4; ++dn) {
#pragma unroll
      for (int r = 0; r < 4; ++r) {
        int t = q0 + lg * 4 + r;
        Y[(size_t)(b * T_SEQ + t) * 1024 + h * 64 + dn * 16 + lc] =
            f2bf(o[dn][r] * lr[r]);
      }
    }
  }
}

extern "C" void kernel_launch(void* const* d_in, const int* in_sizes, int n_in,
                              void* d_out, int out_size, void* d_ws, size_t ws_size,
                              hipStream_t stream) {
  const float* x    = (const float*)d_in[0];  // [4096][1024] f32
  const float* Wqkv = (const float*)d_in[1];  // [1024][3072] f32
  const float* Wo   = (const float*)d_in[2];  // [1024][1024] f32
  for (int i = 0; i < n_in; ++i) {
    if (in_sizes[i] == 4194304) x = (const float*)d_in[i];
    else if (in_sizes[i] == 3145728) Wqkv = (const float*)d_in[i];
    else if (in_sizes[i] == 1048576) Wo = (const float*)d_in[i];
  }
  float* out = (float*)d_out;  // [4096][1024] f32

  ushort* xb    = (ushort*)d_ws;                       // [4096][1024] bf16
  ushort* WqkvT = xb + (size_t)4096 * 1024;            // [3072][1024]
  ushort* WoT   = WqkvT + (size_t)3072 * 1024;         // [1024][1024]
  ushort* QKV   = WoT + (size_t)1024 * 1024;           // [4096][3072]
  ushort* Yb    = QKV + (size_t)4096 * 3072;           // [4096][1024]

  cvt_bf16_k<<<2048, 256, 0, stream>>>(x, xb);
  transpose_cvt2_k<<<dim3(16, 64), 256, 0, stream>>>(Wqkv, Wo, WqkvT, WoT);
  gemm_bt<<<dim3(32, 24), 256, 0, stream>>>(xb, WqkvT, QKV, 4096, 3072, 1024, 0);
  attn_k<<<512, 512, 0, stream>>>(QKV, Yb);
  gemm_bt<<<dim3(32, 8), 256, 0, stream>>>(Yb, WoT, out, 4096, 1024, 1024, 1);
}